// Round 2
// baseline (2790.209 us; speedup 1.0000x reference)
//
#include <hip/hip_runtime.h>
#include <hip/hip_bf16.h>
#include <math.h>

// Problem constants
#define B_   64
#define N_   576
#define D_   768
#define L_   64
#define H_   8
#define HD_  96
#define NB_  (B_*N_)    // 36864 rows
#define ML_  (B_*L_)    // 4096 rows
#define SCALE_ 0.10206207f          // 96^-0.5
#define INV_SQRT_D_ 0.03608439182f  // 1/sqrt(768)

typedef __hip_bfloat16 bf16;

__device__ __forceinline__ float u2f(unsigned short u) { return __uint_as_float(((unsigned)u) << 16); }

// ---------------------------------------------------------------------------
// K1: LayerNorm1 (fp32 in -> fp32 out) + token_score + row sum-of-squares
// grid NB_, block 256 (3 elems/thread)
// ---------------------------------------------------------------------------
__global__ __launch_bounds__(256) void k_ln1(const float* __restrict__ x,
    const float* __restrict__ g, const float* __restrict__ bt,
    const float* __restrict__ sw, const float* __restrict__ sb,
    float* __restrict__ xn, float* __restrict__ ts, float* __restrict__ sq)
{
  int row = blockIdx.x, tid = threadIdx.x;
  const float* xr = x + (size_t)row * D_;
  float v0 = xr[tid], v1 = xr[tid + 256], v2 = xr[tid + 512];
  __shared__ float r1[256], r2[256];
  r1[tid] = v0 + v1 + v2;
  r2[tid] = v0 * v0 + v1 * v1 + v2 * v2;
  __syncthreads();
  for (int o = 128; o > 0; o >>= 1) {
    if (tid < o) { r1[tid] += r1[tid + o]; r2[tid] += r2[tid + o]; }
    __syncthreads();
  }
  float mean = r1[0] * (1.0f / D_);
  float var  = r2[0] * (1.0f / D_) - mean * mean;
  float rstd = rsqrtf(var + 1e-5f);
  __syncthreads();
  float o0 = (v0 - mean) * rstd * g[tid      ] + bt[tid      ];
  float o1 = (v1 - mean) * rstd * g[tid + 256] + bt[tid + 256];
  float o2 = (v2 - mean) * rstd * g[tid + 512] + bt[tid + 512];
  float* xo = xn + (size_t)row * D_;
  xo[tid] = o0; xo[tid + 256] = o1; xo[tid + 512] = o2;
  r1[tid] = o0 * sw[tid] + o1 * sw[tid + 256] + o2 * sw[tid + 512];
  r2[tid] = o0 * o0 + o1 * o1 + o2 * o2;
  __syncthreads();
  for (int o = 128; o > 0; o >>= 1) {
    if (tid < o) { r1[tid] += r1[tid + o]; r2[tid] += r2[tid + o]; }
    __syncthreads();
  }
  if (tid == 0) { ts[row] = r1[0] + sb[0]; sq[row] = r2[0]; }
}

// ---------------------------------------------------------------------------
// K2: pairwise distance matrix dm[b,i,j] (symmetric; compute upper tiles only)
// grid (81, B_), block 256, 64x64 tile, 4x4 microtile
// ---------------------------------------------------------------------------
__global__ __launch_bounds__(256) void k_dm(const float* __restrict__ xn,
    const float* __restrict__ sq, float* __restrict__ dm)
{
  int b = blockIdx.y;
  int ti = blockIdx.x / 9, tj = blockIdx.x % 9;
  if (tj < ti) return;
  __shared__ float AsT[16][68], BsT[16][68];
  int tid = threadIdx.x;
  int ty = tid >> 4, tx = tid & 15;
  int lr = tid >> 2, lk = (tid & 3) * 4;
  const float* Xb = xn + (size_t)b * N_ * D_;
  const float* Arow = Xb + (size_t)(ti * 64 + lr) * D_ + lk;
  const float* Brow = Xb + (size_t)(tj * 64 + lr) * D_ + lk;
  float acc[4][4] = {};
  for (int kt = 0; kt < D_; kt += 16) {
    float4 a4 = *(const float4*)(Arow + kt);
    float4 b4 = *(const float4*)(Brow + kt);
    __syncthreads();
    AsT[lk + 0][lr] = a4.x; AsT[lk + 1][lr] = a4.y; AsT[lk + 2][lr] = a4.z; AsT[lk + 3][lr] = a4.w;
    BsT[lk + 0][lr] = b4.x; BsT[lk + 1][lr] = b4.y; BsT[lk + 2][lr] = b4.z; BsT[lk + 3][lr] = b4.w;
    __syncthreads();
#pragma unroll
    for (int kk = 0; kk < 16; ++kk) {
      float4 av = *(const float4*)&AsT[kk][ty * 4];
      float4 bv = *(const float4*)&BsT[kk][tx * 4];
      float aR[4] = {av.x, av.y, av.z, av.w};
      float bC[4] = {bv.x, bv.y, bv.z, bv.w};
#pragma unroll
      for (int r = 0; r < 4; ++r)
#pragma unroll
        for (int c = 0; c < 4; ++c) acc[r][c] += aR[r] * bC[c];
    }
  }
  const float* sqb = sq + b * N_;
  float* dmb = dm + (size_t)b * N_ * N_;
  int gi0 = ti * 64 + ty * 4, gj0 = tj * 64 + tx * 4;
#pragma unroll
  for (int r = 0; r < 4; ++r) {
    float si = sqb[gi0 + r];
#pragma unroll
    for (int c = 0; c < 4; ++c) {
      float d = si + sqb[gj0 + c] - 2.0f * acc[r][c];
      d = sqrtf(fmaxf(d, 0.0f)) * INV_SQRT_D_;
      dmb[(size_t)(gi0 + r) * N_ + (gj0 + c)] = d;
      dmb[(size_t)(gj0 + c) * N_ + (gi0 + r)] = d;
    }
  }
}

// ---------------------------------------------------------------------------
// K3: kNN density: 5 smallest distances per row -> exp(-mean(d^2)) + noise*1e-6
// grid NB_, block 64 (one wave per row)
// ---------------------------------------------------------------------------
__global__ __launch_bounds__(64) void k_density(const float* __restrict__ dm,
    const float* __restrict__ noise, float* __restrict__ den)
{
  int row = blockIdx.x, lane = threadIdx.x;
  const float* r = dm + (size_t)row * N_;
  float a0 = 1e30f, a1 = 1e30f, a2 = 1e30f, a3 = 1e30f, a4 = 1e30f;
  auto ins5 = [&](float xv) {
    a4 = fminf(a4, xv);
    float t;
    t = fminf(a3, a4); a4 = fmaxf(a3, a4); a3 = t;
    t = fminf(a2, a3); a3 = fmaxf(a2, a3); a2 = t;
    t = fminf(a1, a2); a2 = fmaxf(a1, a2); a1 = t;
    t = fminf(a0, a1); a1 = fmaxf(a0, a1); a0 = t;
  };
#pragma unroll
  for (int t = 0; t < 9; ++t) ins5(r[lane + 64 * t]);
  for (int m = 1; m < 64; m <<= 1) {
    float b0 = __shfl_xor(a0, m), b1 = __shfl_xor(a1, m), b2 = __shfl_xor(a2, m);
    float b3 = __shfl_xor(a3, m), b4 = __shfl_xor(a4, m);
    ins5(b0); ins5(b1); ins5(b2); ins5(b3); ins5(b4);
  }
  if (lane == 0) {
    float ms = (a0 * a0 + a1 * a1 + a2 * a2 + a3 * a3 + a4 * a4) * 0.2f;
    den[row] = expf(-ms) + noise[row] * 1e-6f;
  }
}

// ---------------------------------------------------------------------------
// K4: per-batch max distance (atomicMax on float bits; all values >= 0)
// grid (B_, 81), block 256
// ---------------------------------------------------------------------------
__global__ __launch_bounds__(256) void k_dmax(const float* __restrict__ dm,
    float* __restrict__ dmax)
{
  int b = blockIdx.x, chunk = blockIdx.y, tid = threadIdx.x;
  const float* p = dm + (size_t)b * N_ * N_ + (size_t)chunk * 4096;
  float m = 0.0f;
#pragma unroll
  for (int t = 0; t < 16; ++t) m = fmaxf(m, p[tid + t * 256]);
  __shared__ float r[256];
  r[tid] = m; __syncthreads();
  for (int o = 128; o > 0; o >>= 1) {
    if (tid < o) r[tid] = fmaxf(r[tid], r[tid + o]);
    __syncthreads();
  }
  if (tid == 0) atomicMax((unsigned int*)(dmax + b), __float_as_uint(r[0]));
}

// ---------------------------------------------------------------------------
// K5: dist-to-higher-density + score
// grid NB_, block 64
// ---------------------------------------------------------------------------
__global__ __launch_bounds__(64) void k_dist(const float* __restrict__ dm,
    const float* __restrict__ den, const float* __restrict__ dmax,
    float* __restrict__ score)
{
  int row = blockIdx.x, lane = threadIdx.x;
  int b = row / N_;
  float di = den[row], dx = dmax[b];
  const float* r = dm + (size_t)row * N_;
  const float* db = den + b * N_;
  float m = dx;
#pragma unroll
  for (int t = 0; t < 9; ++t) {
    int j = lane + 64 * t;
    float v = (db[j] > di) ? r[j] : dx;
    m = fminf(m, v);
  }
  for (int msk = 1; msk < 64; msk <<= 1) m = fminf(m, __shfl_xor(m, msk));
  if (lane == 0) score[row] = m * di;
}

// ---------------------------------------------------------------------------
// K6: top-64 scores per batch (descending, ties -> smaller index; matches lax.top_k)
// grid B_, block 256
// ---------------------------------------------------------------------------
__global__ __launch_bounds__(256) void k_topL(const float* __restrict__ score,
    int* __restrict__ idxd)
{
  int b = blockIdx.x, tid = threadIdx.x;
  __shared__ float s[N_];
  __shared__ float rv[256];
  __shared__ int   ri[256];
  for (int j = tid; j < N_; j += 256) s[j] = score[b * N_ + j];
  __syncthreads();
  for (int it = 0; it < L_; ++it) {
    float bv = -1e30f; int bi = 1 << 30;
    for (int j = tid; j < N_; j += 256) {
      float v = s[j];
      if (v > bv || (v == bv && j < bi)) { bv = v; bi = j; }
    }
    rv[tid] = bv; ri[tid] = bi; __syncthreads();
    for (int o = 128; o > 0; o >>= 1) {
      if (tid < o) {
        float v2 = rv[tid + o]; int i2 = ri[tid + o];
        if (v2 > rv[tid] || (v2 == rv[tid] && i2 < ri[tid])) { rv[tid] = v2; ri[tid] = i2; }
      }
      __syncthreads();
    }
    if (tid == 0) { idxd[b * L_ + it] = ri[0]; s[ri[0]] = -1e30f; }
    __syncthreads();
  }
}

// ---------------------------------------------------------------------------
// K7: assign each token to nearest center (argmin over l, first occurrence)
// grid B_, block 576
// ---------------------------------------------------------------------------
__global__ __launch_bounds__(576) void k_assign(const float* __restrict__ dm,
    const int* __restrict__ idxd, int* __restrict__ idxc)
{
  int b = blockIdx.x, n = threadIdx.x;
  __shared__ int ctr[L_];
  if (n < L_) ctr[n] = idxd[b * L_ + n];
  __syncthreads();
  const float* dmb = dm + (size_t)b * N_ * N_;
  float best = 1e30f; int bl = 0;
  for (int l = 0; l < L_; ++l) {
    float v = dmb[(size_t)ctr[l] * N_ + n];
    if (v < best) { best = v; bl = l; }
  }
  idxc[b * N_ + n] = bl;
}

__global__ __launch_bounds__(64) void k_setcenters(const int* __restrict__ idxd,
    int* __restrict__ idxc)
{
  int b = blockIdx.x, l = threadIdx.x;
  idxc[b * N_ + idxd[b * L_ + l]] = l;
}

// ---------------------------------------------------------------------------
// K8: merger (gather form, deterministic):
//   q_input[b,l,:] = sum_{n in cluster l} xn[b,n,:]*exp(ts) / (sum exp(ts)+1e-6)
// grid ML_, block 256
// ---------------------------------------------------------------------------
__global__ __launch_bounds__(256) void k_merge(const float* __restrict__ xn,
    const float* __restrict__ ts, const int* __restrict__ idxc,
    float* __restrict__ qin)
{
  int blk = blockIdx.x;
  int b = blk >> 6, l = blk & 63;
  int tid = threadIdx.x;
  const int* ic = idxc + b * N_;
  const float* tsb = ts + b * N_;
  const float* xb = xn + (size_t)b * N_ * D_;
  float a0 = 0.f, a1 = 0.f, a2 = 0.f, wsum = 0.f;
  for (int n = 0; n < N_; ++n) {
    if (ic[n] == l) {
      float w = expf(tsb[n]);
      wsum += w;
      const float* xr = xb + (size_t)n * D_;
      a0 += w * xr[tid]; a1 += w * xr[tid + 256]; a2 += w * xr[tid + 512];
    }
  }
  float inv = 1.0f / (wsum + 1e-6f);
  float* q = qin + (size_t)blk * D_;
  q[tid] = a0 * inv; q[tid + 256] = a1 * inv; q[tid + 512] = a2 * inv;
}

// ---------------------------------------------------------------------------
// Generic GEMM: C[M,N] = epilogue(A[M,K] (fp32) @ W[K,N] (fp32))
// MODE 0: fp32 out         1: bf16 out (internal k/v cache)
//      2: +bias +res, fp32 out      3: +bias, exact GELU, fp32 out
// grid (M/128, N/64), block 256, 8x4 microtile
// ---------------------------------------------------------------------------
template<int MODE>
__global__ __launch_bounds__(256) void k_gemm(const float* __restrict__ A,
    const float* __restrict__ W, const float* __restrict__ bias,
    const float* __restrict__ res, void* __restrict__ outp,
    int M, int Nd, int Kd)
{
  __shared__ float AsT[16][136];
  __shared__ float Bs[16][68];
  int tid = threadIdx.x;
  int bm = blockIdx.x * 128, bn = blockIdx.y * 64;
  int ty = tid >> 4, tx = tid & 15;
  int am = tid >> 1, ah = (tid & 1) * 8;
  int wkr = tid >> 4, wn = (tid & 15) * 4;
  const float* Ap = A + (size_t)(bm + am) * Kd + ah;
  float acc[8][4] = {};
  for (int kt = 0; kt < Kd; kt += 16) {
    float4 aa0 = *(const float4*)(Ap + kt);
    float4 aa1 = *(const float4*)(Ap + kt + 4);
    float4 w4 = *(const float4*)(W + (size_t)(kt + wkr) * Nd + bn + wn);
    __syncthreads();
    AsT[ah + 0][am] = aa0.x; AsT[ah + 1][am] = aa0.y; AsT[ah + 2][am] = aa0.z; AsT[ah + 3][am] = aa0.w;
    AsT[ah + 4][am] = aa1.x; AsT[ah + 5][am] = aa1.y; AsT[ah + 6][am] = aa1.z; AsT[ah + 7][am] = aa1.w;
    Bs[wkr][wn + 0] = w4.x; Bs[wkr][wn + 1] = w4.y;
    Bs[wkr][wn + 2] = w4.z; Bs[wkr][wn + 3] = w4.w;
    __syncthreads();
#pragma unroll
    for (int kk = 0; kk < 16; ++kk) {
      float4 b4 = *(const float4*)&Bs[kk][tx * 4];
      float4 aL = *(const float4*)&AsT[kk][ty * 8];
      float4 aH = *(const float4*)&AsT[kk][ty * 8 + 4];
      float aR[8] = {aL.x, aL.y, aL.z, aL.w, aH.x, aH.y, aH.z, aH.w};
      float bC[4] = {b4.x, b4.y, b4.z, b4.w};
#pragma unroll
      for (int r = 0; r < 8; ++r)
#pragma unroll
        for (int c = 0; c < 4; ++c) acc[r][c] += aR[r] * bC[c];
    }
  }
  int gn = bn + tx * 4;
  float bv[4] = {0.f, 0.f, 0.f, 0.f};
  if (MODE >= 2) {
    bv[0] = bias[gn]; bv[1] = bias[gn + 1];
    bv[2] = bias[gn + 2]; bv[3] = bias[gn + 3];
  }
#pragma unroll
  for (int r = 0; r < 8; ++r) {
    int gm = bm + ty * 8 + r;
    float o[4];
#pragma unroll
    for (int c = 0; c < 4; ++c) o[c] = acc[r][c];
    if (MODE == 2) {
      float4 r4 = *(const float4*)(res + (size_t)gm * Nd + gn);
      o[0] += bv[0] + r4.x; o[1] += bv[1] + r4.y; o[2] += bv[2] + r4.z; o[3] += bv[3] + r4.w;
    }
    if (MODE == 3) {
#pragma unroll
      for (int c = 0; c < 4; ++c) {
        float v = o[c] + bv[c];
        o[c] = 0.5f * v * (1.0f + erff(v * 0.70710678f));
      }
    }
    if (MODE == 1) {
      unsigned short* ou = (unsigned short*)outp;
      ushort4 s4;
      bf16 h0 = __float2bfloat16(o[0]); bf16 h1 = __float2bfloat16(o[1]);
      bf16 h2 = __float2bfloat16(o[2]); bf16 h3 = __float2bfloat16(o[3]);
      s4.x = *(unsigned short*)&h0; s4.y = *(unsigned short*)&h1;
      s4.z = *(unsigned short*)&h2; s4.w = *(unsigned short*)&h3;
      *(ushort4*)(ou + (size_t)gm * Nd + gn) = s4;
    } else {
      float* of = (float*)outp;
      *(float4*)(of + (size_t)gm * Nd + gn) = make_float4(o[0], o[1], o[2], o[3]);
    }
  }
}

// ---------------------------------------------------------------------------
// K12: fused cross-attention with token-score bias (flash-style over 9 key tiles)
// grid (H_, B_), block 256
// ---------------------------------------------------------------------------
__global__ __launch_bounds__(256) void k_attn(const float* __restrict__ qb,
    const bf16* __restrict__ kb, const bf16* __restrict__ vb,
    const float* __restrict__ ts, float* __restrict__ aout)
{
  int h = blockIdx.x, b = blockIdx.y;
  int tid = threadIdx.x;
  __shared__ float qsT[96][68];     // qsT[k][i]
  __shared__ float kv[6528];        // union: ksT[96][68]  /  vs[64][100]
  __shared__ float sP[64][69];
  __shared__ float marr[64], larr[64], aarr[64], tsb[64];
  const unsigned short* Ku = (const unsigned short*)kb;
  const unsigned short* Vu = (const unsigned short*)vb;
  for (int idx = tid; idx < 1536; idx += 256) {
    int i = idx / 24, kq = (idx % 24) * 4;
    float4 q4 = *(const float4*)(qb + (size_t)(b * 64 + i) * D_ + h * 96 + kq);
    qsT[kq + 0][i] = q4.x; qsT[kq + 1][i] = q4.y; qsT[kq + 2][i] = q4.z; qsT[kq + 3][i] = q4.w;
  }
  if (tid < 64) { marr[tid] = -1e30f; larr[tid] = 0.f; aarr[tid] = 0.f; }
  float O[24];
#pragma unroll
  for (int q = 0; q < 24; ++q) O[q] = 0.f;
  int ty = tid >> 4, tx = tid & 15;
  int iO = tid & 63, jg = tid >> 6, d0 = jg * 24;
  __syncthreads();
  for (int jt = 0; jt < 9; ++jt) {
    int j0 = jt * 64;
    for (int idx = tid; idx < 1536; idx += 256) {
      int j = idx / 24, kq = (idx % 24) * 4;
      ushort4 k4 = *(const ushort4*)(Ku + (size_t)(b * N_ + j0 + j) * D_ + h * 96 + kq);
      kv[(kq + 0) * 68 + j] = u2f(k4.x); kv[(kq + 1) * 68 + j] = u2f(k4.y);
      kv[(kq + 2) * 68 + j] = u2f(k4.z); kv[(kq + 3) * 68 + j] = u2f(k4.w);
    }
    if (tid < 64) tsb[tid] = ts[b * N_ + j0 + tid];
    __syncthreads();
    float sc[4][4] = {};
#pragma unroll 4
    for (int kk = 0; kk < 96; ++kk) {
      float4 qv = *(const float4*)&qsT[kk][ty * 4];
      float4 kv4 = *(const float4*)&kv[kk * 68 + tx * 4];
      float aR[4] = {qv.x, qv.y, qv.z, qv.w};
      float bC[4] = {kv4.x, kv4.y, kv4.z, kv4.w};
#pragma unroll
      for (int r = 0; r < 4; ++r)
#pragma unroll
        for (int c = 0; c < 4; ++c) sc[r][c] += aR[r] * bC[c];
    }
#pragma unroll
    for (int r = 0; r < 4; ++r) {
      float rm = -1e30f;
#pragma unroll
      for (int c = 0; c < 4; ++c) {
        sc[r][c] = sc[r][c] * SCALE_ + tsb[tx * 4 + c];
        rm = fmaxf(rm, sc[r][c]);
      }
      rm = fmaxf(rm, __shfl_xor(rm, 1));
      rm = fmaxf(rm, __shfl_xor(rm, 2));
      rm = fmaxf(rm, __shfl_xor(rm, 4));
      rm = fmaxf(rm, __shfl_xor(rm, 8));
      int i = ty * 4 + r;
      float mold = marr[i];
      float mnew = fmaxf(mold, rm);
      float rs = 0.f;
#pragma unroll
      for (int c = 0; c < 4; ++c) {
        float p = expf(sc[r][c] - mnew);
        sc[r][c] = p; rs += p;
      }
      rs += __shfl_xor(rs, 1); rs += __shfl_xor(rs, 2);
      rs += __shfl_xor(rs, 4); rs += __shfl_xor(rs, 8);
      float alpha = expf(mold - mnew);
      if (tx == 0) { marr[i] = mnew; larr[i] = larr[i] * alpha + rs; aarr[i] = alpha; }
#pragma unroll
      for (int c = 0; c < 4; ++c) sP[i][tx * 4 + c] = sc[r][c];
    }
    __syncthreads();
    // load V tile into kv (vs[64][100])
    for (int idx = tid; idx < 1536; idx += 256) {
      int j = idx / 24, kq = (idx % 24) * 4;
      ushort4 v4 = *(const ushort4*)(Vu + (size_t)(b * N_ + j0 + j) * D_ + h * 96 + kq);
      *(float4*)&kv[j * 100 + kq] = make_float4(u2f(v4.x), u2f(v4.y), u2f(v4.z), u2f(v4.w));
    }
    __syncthreads();
    float al = aarr[iO];
#pragma unroll
    for (int q = 0; q < 24; ++q) O[q] *= al;
#pragma unroll 2
    for (int j = 0; j < 64; ++j) {
      float p = sP[iO][j];
      const float* vp = &kv[j * 100 + d0];
#pragma unroll
      for (int q = 0; q < 6; ++q) {
        float4 vv = *(const float4*)(vp + q * 4);
        O[q * 4 + 0] += p * vv.x; O[q * 4 + 1] += p * vv.y;
        O[q * 4 + 2] += p * vv.z; O[q * 4 + 3] += p * vv.w;
      }
    }
    __syncthreads();
  }
  float linv = 1.0f / larr[iO];
#pragma unroll
  for (int q = 0; q < 24; ++q) O[q] *= linv;
#pragma unroll
  for (int q = 0; q < 6; ++q)
    *(float4*)&kv[iO * 100 + d0 + q * 4] =
        make_float4(O[q * 4 + 0], O[q * 4 + 1], O[q * 4 + 2], O[q * 4 + 3]);
  __syncthreads();
  for (int idx = tid; idx < 6144; idx += 256) {
    int i = idx / 96, d = idx - i * 96;
    aout[(size_t)(b * 64 + i) * D_ + h * 96 + d] = kv[i * 100 + d];
  }
}

// ---------------------------------------------------------------------------
// K14: LayerNorm2 (fp32 in -> fp32 out)
// ---------------------------------------------------------------------------
__global__ __launch_bounds__(256) void k_ln2(const float* __restrict__ f,
    const float* __restrict__ g, const float* __restrict__ bt, float* __restrict__ out)
{
  int row = blockIdx.x, tid = threadIdx.x;
  const float* fr = f + (size_t)row * D_;
  float v0 = fr[tid], v1 = fr[tid + 256], v2 = fr[tid + 512];
  __shared__ float r1[256], r2[256];
  r1[tid] = v0 + v1 + v2;
  r2[tid] = v0 * v0 + v1 * v1 + v2 * v2;
  __syncthreads();
  for (int o = 128; o > 0; o >>= 1) {
    if (tid < o) { r1[tid] += r1[tid + o]; r2[tid] += r2[tid + o]; }
    __syncthreads();
  }
  float mean = r1[0] * (1.0f / D_);
  float var  = r2[0] * (1.0f / D_) - mean * mean;
  float rstd = rsqrtf(var + 1e-5f);
  float* oo = out + (size_t)row * D_;
  oo[tid      ] = (v0 - mean) * rstd * g[tid      ] + bt[tid      ];
  oo[tid + 256] = (v1 - mean) * rstd * g[tid + 256] + bt[tid + 256];
  oo[tid + 512] = (v2 - mean) * rstd * g[tid + 512] + bt[tid + 512];
}

// ---------------------------------------------------------------------------
// Launch. Workspace layout (fp32 units), total ~278 MB:
//   XN[28.3M] | RG[28.3M: dm -> k,v(bf16) -> mlp hidden] | QIN FEAT AOUT QBUF
//   [3.1M each] | TS SQ DEN SCORE [36864 each] | DMAX[64] | IDXD[4096] IDXC[36864]
// ---------------------------------------------------------------------------
extern "C" void kernel_launch(void* const* d_in, const int* in_sizes, int n_in,
                              void* d_out, int out_size, void* d_ws, size_t ws_size,
                              hipStream_t stream)
{
  (void)in_sizes; (void)n_in; (void)out_size; (void)ws_size;
  const float* x    = (const float*)d_in[0];
  const float* nois = (const float*)d_in[1];
  const float* n1g  = (const float*)d_in[2];
  const float* n1b  = (const float*)d_in[3];
  const float* sw   = (const float*)d_in[4];
  const float* sb   = (const float*)d_in[5];
  const float* wq   = (const float*)d_in[6];
  const float* wk   = (const float*)d_in[7];
  const float* wv   = (const float*)d_in[8];
  const float* pw   = (const float*)d_in[9];
  const float* pb   = (const float*)d_in[10];
  const float* n2g  = (const float*)d_in[11];
  const float* n2b  = (const float*)d_in[12];
  const float* f1w  = (const float*)d_in[13];
  const float* f1b  = (const float*)d_in[14];
  const float* f2w  = (const float*)d_in[15];
  const float* f2b  = (const float*)d_in[16];

  float* ws    = (float*)d_ws;
  float* XN    = ws;
  float* RG    = XN + (size_t)NB_ * D_;
  float* QIN   = RG + (size_t)NB_ * D_;
  float* FEAT  = QIN + (size_t)ML_ * D_;
  float* AOUT  = FEAT + (size_t)ML_ * D_;
  float* QBUF  = AOUT + (size_t)ML_ * D_;
  float* TS    = QBUF + (size_t)ML_ * D_;
  float* SQ    = TS + NB_;
  float* DEN   = SQ + NB_;
  float* SCORE = DEN + NB_;
  float* DMAX  = SCORE + NB_;
  int*   IDXD  = (int*)(DMAX + 64);
  int*   IDXC  = IDXD + ML_;
  float* DM    = RG;                      // phase 1
  bf16*  KB    = (bf16*)RG;               // phase 2
  bf16*  VB    = KB + (size_t)NB_ * D_;
  float* HID   = RG;                      // phase 3

  hipMemsetAsync(DMAX, 0, 64 * sizeof(float), stream);
  k_ln1<<<NB_, 256, 0, stream>>>(x, n1g, n1b, sw, sb, XN, TS, SQ);
  k_dm<<<dim3(81, B_), 256, 0, stream>>>(XN, SQ, DM);
  k_density<<<NB_, 64, 0, stream>>>(DM, nois, DEN);
  k_dmax<<<dim3(B_, 81), 256, 0, stream>>>(DM, DMAX);
  k_dist<<<NB_, 64, 0, stream>>>(DM, DEN, DMAX, SCORE);
  k_topL<<<B_, 256, 0, stream>>>(SCORE, IDXD);
  k_assign<<<B_, 576, 0, stream>>>(DM, IDXD, IDXC);
  k_setcenters<<<B_, 64, 0, stream>>>(IDXD, IDXC);
  k_merge<<<ML_, 256, 0, stream>>>(XN, TS, IDXC, QIN);
  k_gemm<0><<<dim3(ML_ / 128, D_ / 64), 256, 0, stream>>>(QIN, wq, nullptr, nullptr, QBUF, ML_, D_, D_);
  k_gemm<1><<<dim3(NB_ / 128, D_ / 64), 256, 0, stream>>>(XN, wk, nullptr, nullptr, KB, NB_, D_, D_);
  k_gemm<1><<<dim3(NB_ / 128, D_ / 64), 256, 0, stream>>>(XN, wv, nullptr, nullptr, VB, NB_, D_, D_);
  k_attn<<<dim3(H_, B_), 256, 0, stream>>>(QBUF, KB, VB, TS, AOUT);
  k_gemm<2><<<dim3(ML_ / 128, D_ / 64), 256, 0, stream>>>(AOUT, pw, pb, QIN, FEAT, ML_, D_, D_);
  k_ln2<<<ML_, 256, 0, stream>>>(FEAT, n2g, n2b, QBUF);
  k_gemm<3><<<dim3(ML_ / 128, (4 * D_) / 64), 256, 0, stream>>>(QBUF, f1w, f1b, nullptr, HID, ML_, 4 * D_, D_);
  k_gemm<2><<<dim3(ML_ / 128, D_ / 64), 256, 0, stream>>>(HID, f2w, f2b, FEAT, d_out, ML_, D_, 4 * D_);
}

// Round 3
// 1289.251 us; speedup vs baseline: 2.1642x; 2.1642x over previous
//
#include <hip/hip_runtime.h>
#include <hip/hip_bf16.h>
#include <math.h>

// Problem constants
#define B_   64
#define N_   576
#define D_   768
#define L_   64
#define H_   8
#define HD_  96
#define NB_  (B_*N_)    // 36864 rows
#define ML_  (B_*L_)    // 4096 rows
#define SCALE_ 0.10206207f          // 96^-0.5
#define INV_SQRT_D_ 0.03608439182f  // 1/sqrt(768)

typedef __hip_bfloat16 bf16;
typedef __attribute__((ext_vector_type(8))) short short8v;   // 8 bf16 (4 VGPRs)
typedef __attribute__((ext_vector_type(4))) float floatx4;   // MFMA C/D

__device__ __forceinline__ float u2f(unsigned short u) { return __uint_as_float(((unsigned)u) << 16); }
__device__ __forceinline__ unsigned short f2bu(float f) {
  bf16 h = __float2bfloat16(f);
  return *(unsigned short*)&h;
}

// ---------------------------------------------------------------------------
// K1: LayerNorm1 (fp32 in -> fp32 out) + token_score + row sum-of-squares
// ---------------------------------------------------------------------------
__global__ __launch_bounds__(256) void k_ln1(const float* __restrict__ x,
    const float* __restrict__ g, const float* __restrict__ bt,
    const float* __restrict__ sw, const float* __restrict__ sb,
    float* __restrict__ xn, float* __restrict__ ts, float* __restrict__ sq)
{
  int row = blockIdx.x, tid = threadIdx.x;
  const float* xr = x + (size_t)row * D_;
  float v0 = xr[tid], v1 = xr[tid + 256], v2 = xr[tid + 512];
  __shared__ float r1[256], r2[256];
  r1[tid] = v0 + v1 + v2;
  r2[tid] = v0 * v0 + v1 * v1 + v2 * v2;
  __syncthreads();
  for (int o = 128; o > 0; o >>= 1) {
    if (tid < o) { r1[tid] += r1[tid + o]; r2[tid] += r2[tid + o]; }
    __syncthreads();
  }
  float mean = r1[0] * (1.0f / D_);
  float var  = r2[0] * (1.0f / D_) - mean * mean;
  float rstd = rsqrtf(var + 1e-5f);
  __syncthreads();
  float o0 = (v0 - mean) * rstd * g[tid      ] + bt[tid      ];
  float o1 = (v1 - mean) * rstd * g[tid + 256] + bt[tid + 256];
  float o2 = (v2 - mean) * rstd * g[tid + 512] + bt[tid + 512];
  float* xo = xn + (size_t)row * D_;
  xo[tid] = o0; xo[tid + 256] = o1; xo[tid + 512] = o2;
  r1[tid] = o0 * sw[tid] + o1 * sw[tid + 256] + o2 * sw[tid + 512];
  r2[tid] = o0 * o0 + o1 * o1 + o2 * o2;
  __syncthreads();
  for (int o = 128; o > 0; o >>= 1) {
    if (tid < o) { r1[tid] += r1[tid + o]; r2[tid] += r2[tid + o]; }
    __syncthreads();
  }
  if (tid == 0) { ts[row] = r1[0] + sb[0]; sq[row] = r2[0]; }
}

// ---------------------------------------------------------------------------
// K2: pairwise distance matrix (fp32 — feeds discrete clustering; keep exact)
// ---------------------------------------------------------------------------
__global__ __launch_bounds__(256) void k_dm(const float* __restrict__ xn,
    const float* __restrict__ sq, float* __restrict__ dm)
{
  int b = blockIdx.y;
  int ti = blockIdx.x / 9, tj = blockIdx.x % 9;
  if (tj < ti) return;
  __shared__ float AsT[16][68], BsT[16][68];
  int tid = threadIdx.x;
  int ty = tid >> 4, tx = tid & 15;
  int lr = tid >> 2, lk = (tid & 3) * 4;
  const float* Xb = xn + (size_t)b * N_ * D_;
  const float* Arow = Xb + (size_t)(ti * 64 + lr) * D_ + lk;
  const float* Brow = Xb + (size_t)(tj * 64 + lr) * D_ + lk;
  float acc[4][4] = {};
  for (int kt = 0; kt < D_; kt += 16) {
    float4 a4 = *(const float4*)(Arow + kt);
    float4 b4 = *(const float4*)(Brow + kt);
    __syncthreads();
    AsT[lk + 0][lr] = a4.x; AsT[lk + 1][lr] = a4.y; AsT[lk + 2][lr] = a4.z; AsT[lk + 3][lr] = a4.w;
    BsT[lk + 0][lr] = b4.x; BsT[lk + 1][lr] = b4.y; BsT[lk + 2][lr] = b4.z; BsT[lk + 3][lr] = b4.w;
    __syncthreads();
#pragma unroll
    for (int kk = 0; kk < 16; ++kk) {
      float4 av = *(const float4*)&AsT[kk][ty * 4];
      float4 bv = *(const float4*)&BsT[kk][tx * 4];
      float aR[4] = {av.x, av.y, av.z, av.w};
      float bC[4] = {bv.x, bv.y, bv.z, bv.w};
#pragma unroll
      for (int r = 0; r < 4; ++r)
#pragma unroll
        for (int c = 0; c < 4; ++c) acc[r][c] += aR[r] * bC[c];
    }
  }
  const float* sqb = sq + b * N_;
  float* dmb = dm + (size_t)b * N_ * N_;
  int gi0 = ti * 64 + ty * 4, gj0 = tj * 64 + tx * 4;
#pragma unroll
  for (int r = 0; r < 4; ++r) {
    float si = sqb[gi0 + r];
#pragma unroll
    for (int c = 0; c < 4; ++c) {
      float d = si + sqb[gj0 + c] - 2.0f * acc[r][c];
      d = sqrtf(fmaxf(d, 0.0f)) * INV_SQRT_D_;
      dmb[(size_t)(gi0 + r) * N_ + (gj0 + c)] = d;
      dmb[(size_t)(gj0 + c) * N_ + (gi0 + r)] = d;
    }
  }
}

// ---------------------------------------------------------------------------
// K3: kNN density
// ---------------------------------------------------------------------------
__global__ __launch_bounds__(64) void k_density(const float* __restrict__ dm,
    const float* __restrict__ noise, float* __restrict__ den)
{
  int row = blockIdx.x, lane = threadIdx.x;
  const float* r = dm + (size_t)row * N_;
  float a0 = 1e30f, a1 = 1e30f, a2 = 1e30f, a3 = 1e30f, a4 = 1e30f;
  auto ins5 = [&](float xv) {
    a4 = fminf(a4, xv);
    float t;
    t = fminf(a3, a4); a4 = fmaxf(a3, a4); a3 = t;
    t = fminf(a2, a3); a3 = fmaxf(a2, a3); a2 = t;
    t = fminf(a1, a2); a2 = fmaxf(a1, a2); a1 = t;
    t = fminf(a0, a1); a1 = fmaxf(a0, a1); a0 = t;
  };
#pragma unroll
  for (int t = 0; t < 9; ++t) ins5(r[lane + 64 * t]);
  for (int m = 1; m < 64; m <<= 1) {
    float b0 = __shfl_xor(a0, m), b1 = __shfl_xor(a1, m), b2 = __shfl_xor(a2, m);
    float b3 = __shfl_xor(a3, m), b4 = __shfl_xor(a4, m);
    ins5(b0); ins5(b1); ins5(b2); ins5(b3); ins5(b4);
  }
  if (lane == 0) {
    float ms = (a0 * a0 + a1 * a1 + a2 * a2 + a3 * a3 + a4 * a4) * 0.2f;
    den[row] = expf(-ms) + noise[row] * 1e-6f;
  }
}

// ---------------------------------------------------------------------------
// K4: per-batch max distance
// ---------------------------------------------------------------------------
__global__ __launch_bounds__(256) void k_dmax(const float* __restrict__ dm,
    float* __restrict__ dmax)
{
  int b = blockIdx.x, chunk = blockIdx.y, tid = threadIdx.x;
  const float* p = dm + (size_t)b * N_ * N_ + (size_t)chunk * 4096;
  float m = 0.0f;
#pragma unroll
  for (int t = 0; t < 16; ++t) m = fmaxf(m, p[tid + t * 256]);
  __shared__ float r[256];
  r[tid] = m; __syncthreads();
  for (int o = 128; o > 0; o >>= 1) {
    if (tid < o) r[tid] = fmaxf(r[tid], r[tid + o]);
    __syncthreads();
  }
  if (tid == 0) atomicMax((unsigned int*)(dmax + b), __float_as_uint(r[0]));
}

// ---------------------------------------------------------------------------
// K5: dist-to-higher-density + score
// ---------------------------------------------------------------------------
__global__ __launch_bounds__(64) void k_dist(const float* __restrict__ dm,
    const float* __restrict__ den, const float* __restrict__ dmax,
    float* __restrict__ score)
{
  int row = blockIdx.x, lane = threadIdx.x;
  int b = row / N_;
  float di = den[row], dx = dmax[b];
  const float* r = dm + (size_t)row * N_;
  const float* db = den + b * N_;
  float m = dx;
#pragma unroll
  for (int t = 0; t < 9; ++t) {
    int j = lane + 64 * t;
    float v = (db[j] > di) ? r[j] : dx;
    m = fminf(m, v);
  }
  for (int msk = 1; msk < 64; msk <<= 1) m = fminf(m, __shfl_xor(m, msk));
  if (lane == 0) score[row] = m * di;
}

// ---------------------------------------------------------------------------
// K6: top-64 scores per batch
// ---------------------------------------------------------------------------
__global__ __launch_bounds__(256) void k_topL(const float* __restrict__ score,
    int* __restrict__ idxd)
{
  int b = blockIdx.x, tid = threadIdx.x;
  __shared__ float s[N_];
  __shared__ float rv[256];
  __shared__ int   ri[256];
  for (int j = tid; j < N_; j += 256) s[j] = score[b * N_ + j];
  __syncthreads();
  for (int it = 0; it < L_; ++it) {
    float bv = -1e30f; int bi = 1 << 30;
    for (int j = tid; j < N_; j += 256) {
      float v = s[j];
      if (v > bv || (v == bv && j < bi)) { bv = v; bi = j; }
    }
    rv[tid] = bv; ri[tid] = bi; __syncthreads();
    for (int o = 128; o > 0; o >>= 1) {
      if (tid < o) {
        float v2 = rv[tid + o]; int i2 = ri[tid + o];
        if (v2 > rv[tid] || (v2 == rv[tid] && i2 < ri[tid])) { rv[tid] = v2; ri[tid] = i2; }
      }
      __syncthreads();
    }
    if (tid == 0) { idxd[b * L_ + it] = ri[0]; s[ri[0]] = -1e30f; }
    __syncthreads();
  }
}

// ---------------------------------------------------------------------------
// K7: assign tokens to nearest center
// ---------------------------------------------------------------------------
__global__ __launch_bounds__(576) void k_assign(const float* __restrict__ dm,
    const int* __restrict__ idxd, int* __restrict__ idxc)
{
  int b = blockIdx.x, n = threadIdx.x;
  __shared__ int ctr[L_];
  if (n < L_) ctr[n] = idxd[b * L_ + n];
  __syncthreads();
  const float* dmb = dm + (size_t)b * N_ * N_;
  float best = 1e30f; int bl = 0;
  for (int l = 0; l < L_; ++l) {
    float v = dmb[(size_t)ctr[l] * N_ + n];
    if (v < best) { best = v; bl = l; }
  }
  idxc[b * N_ + n] = bl;
}

__global__ __launch_bounds__(64) void k_setcenters(const int* __restrict__ idxd,
    int* __restrict__ idxc)
{
  int b = blockIdx.x, l = threadIdx.x;
  idxc[b * N_ + idxd[b * L_ + l]] = l;
}

// ---------------------------------------------------------------------------
// K8: merger (gather form)
// ---------------------------------------------------------------------------
__global__ __launch_bounds__(256) void k_merge(const float* __restrict__ xn,
    const float* __restrict__ ts, const int* __restrict__ idxc,
    float* __restrict__ qin)
{
  int blk = blockIdx.x;
  int b = blk >> 6, l = blk & 63;
  int tid = threadIdx.x;
  const int* ic = idxc + b * N_;
  const float* tsb = ts + b * N_;
  const float* xb = xn + (size_t)b * N_ * D_;
  float a0 = 0.f, a1 = 0.f, a2 = 0.f, wsum = 0.f;
  for (int n = 0; n < N_; ++n) {
    if (ic[n] == l) {
      float w = expf(tsb[n]);
      wsum += w;
      const float* xr = xb + (size_t)n * D_;
      a0 += w * xr[tid]; a1 += w * xr[tid + 256]; a2 += w * xr[tid + 512];
    }
  }
  float inv = 1.0f / (wsum + 1e-6f);
  float* q = qin + (size_t)blk * D_;
  q[tid] = a0 * inv; q[tid + 256] = a1 * inv; q[tid + 512] = a2 * inv;
}

// ---------------------------------------------------------------------------
// Weight transpose + bf16 cast: W[K,N] fp32 -> WT[N,K] bf16
// grid (K/32, N/32), block 256
// ---------------------------------------------------------------------------
__global__ __launch_bounds__(256) void k_wt(const float* __restrict__ W,
    bf16* __restrict__ WT, int K, int N)
{
  __shared__ float t[32][33];
  int k0 = blockIdx.x * 32, n0 = blockIdx.y * 32;
  int tid = threadIdx.x;
  int r = tid >> 3, c4 = (tid & 7) * 4;
  float4 v = *(const float4*)(W + (size_t)(k0 + r) * N + n0 + c4);
  t[r][c4] = v.x; t[r][c4 + 1] = v.y; t[r][c4 + 2] = v.z; t[r][c4 + 3] = v.w;
  __syncthreads();
  unsigned short* o = (unsigned short*)WT;
  ushort4 s4;
  s4.x = f2bu(t[c4 + 0][r]); s4.y = f2bu(t[c4 + 1][r]);
  s4.z = f2bu(t[c4 + 2][r]); s4.w = f2bu(t[c4 + 3][r]);
  *(ushort4*)(o + (size_t)(n0 + r) * K + k0 + c4) = s4;
}

// ---------------------------------------------------------------------------
// MFMA GEMM: C[M,N] = epilogue(A[M,K] @ WT[N,K]^T), bf16 MFMA, fp32 accum.
// 128x128 tile, 4 waves, each wave 4x4 of 16x16x32 MFMA tiles.
// ASRC 0: A fp32 (cast to bf16 in staging)   1: A bf16
// EPI  0: bf16 out, no bias
//      1: +bias(fp32) +res(fp32) -> fp32 out
//      2: +bias(fp32), exact GELU -> bf16 out
// LDS rows padded to 40 ushorts (80 B): fragment ds_read_b128 is 2-way = free
// ---------------------------------------------------------------------------
template<int EPI, int ASRC>
__global__ __launch_bounds__(256) void k_mgemm(const void* __restrict__ Ap_,
    const bf16* __restrict__ Wt, const float* __restrict__ bias,
    const float* __restrict__ res, void* __restrict__ outp,
    int M, int Nd, int Kd)
{
  __shared__ __align__(16) unsigned short As[128 * 40];
  __shared__ __align__(16) unsigned short Bs[128 * 40];
  int tid = threadIdx.x;
  int bm = blockIdx.x * 128, bn = blockIdx.y * 128;
  int wave = tid >> 6, lane = tid & 63;
  int wr = (wave >> 1) * 64, wc = (wave & 1) * 64;
  int mloc = lane & 15, quad = lane >> 4;

  floatx4 acc[4][4];
#pragma unroll
  for (int i = 0; i < 4; ++i)
#pragma unroll
    for (int j = 0; j < 4; ++j)
      acc[i][j] = (floatx4){0.f, 0.f, 0.f, 0.f};

  const unsigned short* Wu = (const unsigned short*)Wt;
  for (int kt = 0; kt < Kd; kt += 32) {
    __syncthreads();
#pragma unroll
    for (int it = 0; it < 2; ++it) {
      int idx = tid + it * 256;          // 0..511
      int r = idx >> 2, c = idx & 3;     // row 0..127, 8-elem chunk 0..3
      // A chunk
      uint4 pk;
      if (ASRC == 0) {
        const float* A = (const float*)Ap_;
        const float* ap = A + (size_t)(bm + r) * Kd + kt + c * 8;
        float4 f0 = *(const float4*)ap;
        float4 f1 = *(const float4*)(ap + 4);
        pk.x = (unsigned)f2bu(f0.x) | ((unsigned)f2bu(f0.y) << 16);
        pk.y = (unsigned)f2bu(f0.z) | ((unsigned)f2bu(f0.w) << 16);
        pk.z = (unsigned)f2bu(f1.x) | ((unsigned)f2bu(f1.y) << 16);
        pk.w = (unsigned)f2bu(f1.z) | ((unsigned)f2bu(f1.w) << 16);
      } else {
        const unsigned short* A = (const unsigned short*)Ap_;
        pk = *(const uint4*)(A + (size_t)(bm + r) * Kd + kt + c * 8);
      }
      *(uint4*)&As[r * 40 + c * 8] = pk;
      // B chunk (WT[N][K] bf16)
      uint4 wb = *(const uint4*)(Wu + (size_t)(bn + r) * Kd + kt + c * 8);
      *(uint4*)&Bs[r * 40 + c * 8] = wb;
    }
    __syncthreads();
    short8v af[4], bf[4];
#pragma unroll
    for (int i = 0; i < 4; ++i)
      af[i] = *(const short8v*)&As[(wr + i * 16 + mloc) * 40 + quad * 8];
#pragma unroll
    for (int j = 0; j < 4; ++j)
      bf[j] = *(const short8v*)&Bs[(wc + j * 16 + mloc) * 40 + quad * 8];
#pragma unroll
    for (int i = 0; i < 4; ++i)
#pragma unroll
      for (int j = 0; j < 4; ++j)
        acc[i][j] = __builtin_amdgcn_mfma_f32_16x16x32_bf16(af[i], bf[j], acc[i][j], 0, 0, 0);
  }

  // Epilogue. C/D layout: col = lane&15, row = quad*4 + reg [m89/m91]
  float bv[4] = {0.f, 0.f, 0.f, 0.f};
  if (EPI >= 1) {
#pragma unroll
    for (int j = 0; j < 4; ++j) bv[j] = bias[bn + wc + j * 16 + mloc];
  }
#pragma unroll
  for (int i = 0; i < 4; ++i) {
    int gr0 = bm + wr + i * 16 + quad * 4;
#pragma unroll
    for (int j = 0; j < 4; ++j) {
      int gc = bn + wc + j * 16 + mloc;
#pragma unroll
      for (int reg = 0; reg < 4; ++reg) {
        float v = acc[i][j][reg];
        size_t off = (size_t)(gr0 + reg) * Nd + gc;
        if (EPI == 0) {
          ((unsigned short*)outp)[off] = f2bu(v);
        } else if (EPI == 1) {
          ((float*)outp)[off] = v + bv[j] + res[off];
        } else {
          v += bv[j];
          v = 0.5f * v * (1.0f + erff(v * 0.70710678f));
          ((unsigned short*)outp)[off] = f2bu(v);
        }
      }
    }
  }
}

// ---------------------------------------------------------------------------
// K12: fused cross-attention with token-score bias (q bf16, k/v bf16)
// grid (H_, B_), block 256
// ---------------------------------------------------------------------------
__global__ __launch_bounds__(256) void k_attn(const bf16* __restrict__ qb,
    const bf16* __restrict__ kb, const bf16* __restrict__ vb,
    const float* __restrict__ ts, float* __restrict__ aout)
{
  int h = blockIdx.x, b = blockIdx.y;
  int tid = threadIdx.x;
  __shared__ float qsT[96][68];     // qsT[k][i]
  __shared__ float kv[6528];        // union: ksT[96][68]  /  vs[64][100]
  __shared__ float sP[64][69];
  __shared__ float marr[64], larr[64], aarr[64], tsb[64];
  const unsigned short* Qu = (const unsigned short*)qb;
  const unsigned short* Ku = (const unsigned short*)kb;
  const unsigned short* Vu = (const unsigned short*)vb;
  for (int idx = tid; idx < 1536; idx += 256) {
    int i = idx / 24, kq = (idx % 24) * 4;
    ushort4 q4 = *(const ushort4*)(Qu + (size_t)(b * 64 + i) * D_ + h * 96 + kq);
    qsT[kq + 0][i] = u2f(q4.x); qsT[kq + 1][i] = u2f(q4.y);
    qsT[kq + 2][i] = u2f(q4.z); qsT[kq + 3][i] = u2f(q4.w);
  }
  if (tid < 64) { marr[tid] = -1e30f; larr[tid] = 0.f; aarr[tid] = 0.f; }
  float O[24];
#pragma unroll
  for (int q = 0; q < 24; ++q) O[q] = 0.f;
  int ty = tid >> 4, tx = tid & 15;
  int iO = tid & 63, jg = tid >> 6, d0 = jg * 24;
  __syncthreads();
  for (int jt = 0; jt < 9; ++jt) {
    int j0 = jt * 64;
    for (int idx = tid; idx < 1536; idx += 256) {
      int j = idx / 24, kq = (idx % 24) * 4;
      ushort4 k4 = *(const ushort4*)(Ku + (size_t)(b * N_ + j0 + j) * D_ + h * 96 + kq);
      kv[(kq + 0) * 68 + j] = u2f(k4.x); kv[(kq + 1) * 68 + j] = u2f(k4.y);
      kv[(kq + 2) * 68 + j] = u2f(k4.z); kv[(kq + 3) * 68 + j] = u2f(k4.w);
    }
    if (tid < 64) tsb[tid] = ts[b * N_ + j0 + tid];
    __syncthreads();
    float sc[4][4] = {};
#pragma unroll 4
    for (int kk = 0; kk < 96; ++kk) {
      float4 qv = *(const float4*)&qsT[kk][ty * 4];
      float4 kv4 = *(const float4*)&kv[kk * 68 + tx * 4];
      float aR[4] = {qv.x, qv.y, qv.z, qv.w};
      float bC[4] = {kv4.x, kv4.y, kv4.z, kv4.w};
#pragma unroll
      for (int r = 0; r < 4; ++r)
#pragma unroll
        for (int c = 0; c < 4; ++c) sc[r][c] += aR[r] * bC[c];
    }
#pragma unroll
    for (int r = 0; r < 4; ++r) {
      float rm = -1e30f;
#pragma unroll
      for (int c = 0; c < 4; ++c) {
        sc[r][c] = sc[r][c] * SCALE_ + tsb[tx * 4 + c];
        rm = fmaxf(rm, sc[r][c]);
      }
      rm = fmaxf(rm, __shfl_xor(rm, 1));
      rm = fmaxf(rm, __shfl_xor(rm, 2));
      rm = fmaxf(rm, __shfl_xor(rm, 4));
      rm = fmaxf(rm, __shfl_xor(rm, 8));
      int i = ty * 4 + r;
      float mold = marr[i];
      float mnew = fmaxf(mold, rm);
      float rs = 0.f;
#pragma unroll
      for (int c = 0; c < 4; ++c) {
        float p = expf(sc[r][c] - mnew);
        sc[r][c] = p; rs += p;
      }
      rs += __shfl_xor(rs, 1); rs += __shfl_xor(rs, 2);
      rs += __shfl_xor(rs, 4); rs += __shfl_xor(rs, 8);
      float alpha = expf(mold - mnew);
      if (tx == 0) { marr[i] = mnew; larr[i] = larr[i] * alpha + rs; aarr[i] = alpha; }
#pragma unroll
      for (int c = 0; c < 4; ++c) sP[i][tx * 4 + c] = sc[r][c];
    }
    __syncthreads();
    for (int idx = tid; idx < 1536; idx += 256) {
      int j = idx / 24, kq = (idx % 24) * 4;
      ushort4 v4 = *(const ushort4*)(Vu + (size_t)(b * N_ + j0 + j) * D_ + h * 96 + kq);
      *(float4*)&kv[j * 100 + kq] = make_float4(u2f(v4.x), u2f(v4.y), u2f(v4.z), u2f(v4.w));
    }
    __syncthreads();
    float al = aarr[iO];
#pragma unroll
    for (int q = 0; q < 24; ++q) O[q] *= al;
#pragma unroll 2
    for (int j = 0; j < 64; ++j) {
      float p = sP[iO][j];
      const float* vp = &kv[j * 100 + d0];
#pragma unroll
      for (int q = 0; q < 6; ++q) {
        float4 vv = *(const float4*)(vp + q * 4);
        O[q * 4 + 0] += p * vv.x; O[q * 4 + 1] += p * vv.y;
        O[q * 4 + 2] += p * vv.z; O[q * 4 + 3] += p * vv.w;
      }
    }
    __syncthreads();
  }
  float linv = 1.0f / larr[iO];
#pragma unroll
  for (int q = 0; q < 24; ++q) O[q] *= linv;
#pragma unroll
  for (int q = 0; q < 6; ++q)
    *(float4*)&kv[iO * 100 + d0 + q * 4] =
        make_float4(O[q * 4 + 0], O[q * 4 + 1], O[q * 4 + 2], O[q * 4 + 3]);
  __syncthreads();
  for (int idx = tid; idx < 6144; idx += 256) {
    int i = idx / 96, d = idx - i * 96;
    aout[(size_t)(b * 64 + i) * D_ + h * 96 + d] = kv[i * 100 + d];
  }
}

// ---------------------------------------------------------------------------
// K14: LayerNorm2 (fp32 in -> fp32 out)
// ---------------------------------------------------------------------------
__global__ __launch_bounds__(256) void k_ln2(const float* __restrict__ f,
    const float* __restrict__ g, const float* __restrict__ bt, float* __restrict__ out)
{
  int row = blockIdx.x, tid = threadIdx.x;
  const float* fr = f + (size_t)row * D_;
  float v0 = fr[tid], v1 = fr[tid + 256], v2 = fr[tid + 512];
  __shared__ float r1[256], r2[256];
  r1[tid] = v0 + v1 + v2;
  r2[tid] = v0 * v0 + v1 * v1 + v2 * v2;
  __syncthreads();
  for (int o = 128; o > 0; o >>= 1) {
    if (tid < o) { r1[tid] += r1[tid + o]; r2[tid] += r2[tid + o]; }
    __syncthreads();
  }
  float mean = r1[0] * (1.0f / D_);
  float var  = r2[0] * (1.0f / D_) - mean * mean;
  float rstd = rsqrtf(var + 1e-5f);
  float* oo = out + (size_t)row * D_;
  oo[tid      ] = (v0 - mean) * rstd * g[tid      ] + bt[tid      ];
  oo[tid + 256] = (v1 - mean) * rstd * g[tid + 256] + bt[tid + 256];
  oo[tid + 512] = (v2 - mean) * rstd * g[tid + 512] + bt[tid + 512];
}

// ---------------------------------------------------------------------------
// Launch. Workspace (float units), ~298 MB total:
// XN[28.3M] | RG[28.3M: dm -> KB/VB bf16 -> HID bf16] | QIN | FEAT | AOUT |
// QBUF(ln2 out) [3.1M each] | QB16 bf16 | WTQ..WT2 bf16 | TS SQ DEN SCORE |
// DMAX | IDXD IDXC
// ---------------------------------------------------------------------------
extern "C" void kernel_launch(void* const* d_in, const int* in_sizes, int n_in,
                              void* d_out, int out_size, void* d_ws, size_t ws_size,
                              hipStream_t stream)
{
  (void)in_sizes; (void)n_in; (void)out_size; (void)ws_size;
  const float* x    = (const float*)d_in[0];
  const float* nois = (const float*)d_in[1];
  const float* n1g  = (const float*)d_in[2];
  const float* n1b  = (const float*)d_in[3];
  const float* sw   = (const float*)d_in[4];
  const float* sb   = (const float*)d_in[5];
  const float* wq   = (const float*)d_in[6];
  const float* wk   = (const float*)d_in[7];
  const float* wv   = (const float*)d_in[8];
  const float* pw   = (const float*)d_in[9];
  const float* pb   = (const float*)d_in[10];
  const float* n2g  = (const float*)d_in[11];
  const float* n2b  = (const float*)d_in[12];
  const float* f1w  = (const float*)d_in[13];
  const float* f1b  = (const float*)d_in[14];
  const float* f2w  = (const float*)d_in[15];
  const float* f2b  = (const float*)d_in[16];

  float* ws    = (float*)d_ws;
  float* XN    = ws;
  float* RG    = XN + (size_t)NB_ * D_;
  float* QIN   = RG + (size_t)NB_ * D_;
  float* FEAT  = QIN + (size_t)ML_ * D_;
  float* AOUT  = FEAT + (size_t)ML_ * D_;
  float* QBUF  = AOUT + (size_t)ML_ * D_;
  float* P     = QBUF + (size_t)ML_ * D_;
  bf16*  QB16  = (bf16*)P;             P += (size_t)ML_ * D_ / 2;
  bf16*  WTQ   = (bf16*)P;             P += (size_t)D_ * D_ / 2;
  bf16*  WTK   = (bf16*)P;             P += (size_t)D_ * D_ / 2;
  bf16*  WTV   = (bf16*)P;             P += (size_t)D_ * D_ / 2;
  bf16*  WTP   = (bf16*)P;             P += (size_t)D_ * D_ / 2;
  bf16*  WT1   = (bf16*)P;             P += (size_t)D_ * 4 * D_ / 2;
  bf16*  WT2   = (bf16*)P;             P += (size_t)D_ * 4 * D_ / 2;
  float* TS    = P;
  float* SQ    = TS + NB_;
  float* DEN   = SQ + NB_;
  float* SCORE = DEN + NB_;
  float* DMAX  = SCORE + NB_;
  int*   IDXD  = (int*)(DMAX + 64);
  int*   IDXC  = IDXD + ML_;
  float* DM    = RG;                      // phase 1
  bf16*  KB    = (bf16*)RG;               // phase 2
  bf16*  VB    = KB + (size_t)NB_ * D_;
  bf16*  HID   = (bf16*)RG;               // phase 3 (bf16 [4096][3072])

  hipMemsetAsync(DMAX, 0, 64 * sizeof(float), stream);
  // Weight transposes (fp32 [K,N] -> bf16 [N,K])
  k_wt<<<dim3(24, 24), 256, 0, stream>>>(wq, WTQ, D_, D_);
  k_wt<<<dim3(24, 24), 256, 0, stream>>>(wk, WTK, D_, D_);
  k_wt<<<dim3(24, 24), 256, 0, stream>>>(wv, WTV, D_, D_);
  k_wt<<<dim3(24, 24), 256, 0, stream>>>(pw, WTP, D_, D_);
  k_wt<<<dim3(24, 96), 256, 0, stream>>>(f1w, WT1, D_, 4 * D_);
  k_wt<<<dim3(96, 24), 256, 0, stream>>>(f2w, WT2, 4 * D_, D_);

  k_ln1<<<NB_, 256, 0, stream>>>(x, n1g, n1b, sw, sb, XN, TS, SQ);
  k_dm<<<dim3(81, B_), 256, 0, stream>>>(XN, SQ, DM);
  k_density<<<NB_, 64, 0, stream>>>(DM, nois, DEN);
  k_dmax<<<dim3(B_, 81), 256, 0, stream>>>(DM, DMAX);
  k_dist<<<NB_, 64, 0, stream>>>(DM, DEN, DMAX, SCORE);
  k_topL<<<B_, 256, 0, stream>>>(SCORE, IDXD);
  k_assign<<<B_, 576, 0, stream>>>(DM, IDXD, IDXC);
  k_setcenters<<<B_, 64, 0, stream>>>(IDXD, IDXC);
  k_merge<<<ML_, 256, 0, stream>>>(XN, TS, IDXC, QIN);

  k_mgemm<0, 0><<<dim3(ML_ / 128, D_ / 128), 256, 0, stream>>>(
      QIN, WTQ, nullptr, nullptr, QB16, ML_, D_, D_);
  k_mgemm<0, 0><<<dim3(NB_ / 128, D_ / 128), 256, 0, stream>>>(
      XN, WTK, nullptr, nullptr, KB, NB_, D_, D_);
  k_mgemm<0, 0><<<dim3(NB_ / 128, D_ / 128), 256, 0, stream>>>(
      XN, WTV, nullptr, nullptr, VB, NB_, D_, D_);
  k_attn<<<dim3(H_, B_), 256, 0, stream>>>(QB16, KB, VB, TS, AOUT);
  k_mgemm<1, 0><<<dim3(ML_ / 128, D_ / 128), 256, 0, stream>>>(
      AOUT, WTP, pb, QIN, FEAT, ML_, D_, D_);
  k_ln2<<<ML_, 256, 0, stream>>>(FEAT, n2g, n2b, QBUF);
  k_mgemm<2, 0><<<dim3(ML_ / 128, (4 * D_) / 128), 256, 0, stream>>>(
      QBUF, WT1, f1b, nullptr, HID, ML_, 4 * D_, D_);
  k_mgemm<1, 1><<<dim3(ML_ / 128, D_ / 128), 256, 0, stream>>>(
      HID, WT2, f2b, FEAT, d_out, ML_, D_, 4 * D_);
}